// Round 14
// baseline (49.932 us; speedup 1.0000x reference)
//
#include <hip/hip_runtime.h>
#include <hip/hip_bf16.h>

// out[b,v] = dot(OT[b, pid[v], :], W[v, :]) + bias[v]
// B=32, Q=180, H=768, V=19004. fp32 in/out, bf16 MFMA inside.
#define BB 32
#define QQ 180
#define HH 768
#define VV 19004
#define PB 128       // v's per pair-block (2 MFMA column tiles)
#define KQ 192       // K per quarter (6 MFMA K-steps of 32)
#define SB 19008     // res stride (pos dim)
#define MAXP 360     // max pair descriptors
#define ST 200       // OT LDS row stride in bf16 elems (192 + 8 pad)
#define NB 80        // prep blocks
#define CH 238       // v's per prep block (80*238 = 19040 >= VV)

// ws layout (bytes)
#define WS_H      0        // NB*QQ ints = 57600
#define WS_BASE   65536    // NB*QQ ints = 57600
#define WS_NTOT   131072   // 1 int
#define WS_DESC   132096   // MAXP int4 = 5760
#define WS_SORTED 140288   // VV ints = 76016
#define WS_POSOF  217088   // VV ints = 76016
#define WS_RES    294912   // 4 * 32 * 19008 * 4 = 9,732,096

typedef __attribute__((ext_vector_type(8))) short short8v;  // 8 bf16 (4 VGPR)
typedef __attribute__((ext_vector_type(4))) float f32x4;

__device__ __forceinline__ short f2bf(float f) {  // RNE fp32->bf16
    unsigned u = __builtin_bit_cast(unsigned, f);
    u += 0x7FFFu + ((u >> 16) & 1u);
    return (short)(u >> 16);
}

// ---------- prep 1: per-block LDS histograms ----------
__global__ void hist_k(const int* __restrict__ pid, int* __restrict__ h) {
    __shared__ int lc[QQ];
    const int t = threadIdx.x, b = blockIdx.x;
    if (t < QQ) lc[t] = 0;
    __syncthreads();
    const int v = b * CH + t;
    if (t < CH && v < VV) atomicAdd(&lc[pid[v]], 1);
    __syncthreads();
    if (t < QQ) h[b * QQ + t] = lc[t];
}

// ---------- prep 2: column-sum + q-scan + PAIR desc + scatter bases ----------
__global__ void scan_k(const int* __restrict__ h, int* __restrict__ base,
                       int4* __restrict__ desc, int* __restrict__ ntot) {
    __shared__ int s1[256];
    __shared__ int s2[256];
    const int t = threadIdx.x;
    int c = 0;
    if (t < QQ)
        for (int i = 0; i < NB; ++i) c += h[i * QQ + t];
    s1[t] = c;
    __syncthreads();
    for (int off = 1; off < 256; off <<= 1) {
        int a = (t >= off) ? s1[t - off] : 0;
        __syncthreads();
        s1[t] += a;
        __syncthreads();
    }
    const int qs = s1[t] - c;              // exclusive prefix over q
    const int nch = (c + PB - 1) / PB;     // pairs for this q (128-wide)
    s2[t] = nch;
    __syncthreads();
    for (int off = 1; off < 256; off <<= 1) {
        int a = (t >= off) ? s2[t - off] : 0;
        __syncthreads();
        s2[t] += a;
        __syncthreads();
    }
    if (t < QQ) {
        const int cb = s2[t] - nch;
        for (int j = 0; j < nch; ++j)
            desc[cb + j] = make_int4(t, qs + j * PB, min(PB, c - j * PB), 0);
        int run = qs;                       // per-block scatter bases
        for (int i = 0; i < NB; ++i) {
            base[i * QQ + t] = run;
            run += h[i * QQ + t];
        }
    }
    if (t == 255) *ntot = s2[255];
}

// ---------- prep 3: scatter via per-block LDS cursors ----------
__global__ void scatter_k(const int* __restrict__ pid, const int* __restrict__ base,
                          int* __restrict__ sorted, int* __restrict__ posOf) {
    __shared__ int cur[QQ];
    const int t = threadIdx.x, b = blockIdx.x;
    if (t < QQ) cur[t] = base[b * QQ + t];
    __syncthreads();
    const int v = b * CH + t;
    if (t < CH && v < VV) {
        const int q = pid[v];
        const int pos = atomicAdd(&cur[q], 1);
        sorted[pos] = v;
        posOf[v] = pos;
    }
}

// ---------- main: MFMA 16x16x32 bf16, block = (pair, K-quarter) ----------
// grid = 4*MAXP. p = bid>>2, kh = bid&3; desc[p] = (q, start, len<=128).
// 4 waves; wave w covers pair-local v {16w+co} (tile A) and {64+16w+co}
// (tile B). OT quarter staged once per block (vs once per 64-v chunk before:
// halves OT traffic). One-shot pre-barrier burst: 24 float4/lane (12 per
// v-tile, 6 K-steps each = full KQ=192). A-frags from LDS in-loop (R7 shape).
__launch_bounds__(256)
__global__ void main_k(const float* __restrict__ OT, const float* __restrict__ W,
                       const int* __restrict__ sorted, const int4* __restrict__ desc,
                       const int* __restrict__ ntot, float* __restrict__ res) {
    const int np = *ntot;
    const int bid = blockIdx.x;
    const int p = bid >> 2;
    if (p >= np) return;
    const int kh = bid & 3;
    const int4 d = desc[p];
    const int q     = __builtin_amdgcn_readfirstlane(d.x);
    const int start = __builtin_amdgcn_readfirstlane(d.y);
    const int len   = __builtin_amdgcn_readfirstlane(d.z);
    const int tid = threadIdx.x;

    __shared__ short OTlds[BB * ST];  // 12,800 B

    // stage OT[0..31][q][kh*192 .. +192) as bf16 (coalesced fp32 reads)
    {
        const int r = tid >> 3;   // b row 0..31
        const int o = tid & 7;    // octet
        const float* src = OT + ((size_t)r * QQ + q) * HH + kh * KQ + o * 8;
        short* dst = &OTlds[r * ST + o * 8];
#pragma unroll
        for (int it = 0; it < 3; ++it) {
            const float4 f0 = *(const float4*)(src + it * 64);
            const float4 f1 = *(const float4*)(src + it * 64 + 4);
            short8v s;
            s[0] = f2bf(f0.x); s[1] = f2bf(f0.y); s[2] = f2bf(f0.z); s[3] = f2bf(f0.w);
            s[4] = f2bf(f1.x); s[5] = f2bf(f1.y); s[6] = f2bf(f1.z); s[7] = f2bf(f1.w);
            *(short8v*)(dst + it * 64) = s;
        }
    }

    const int lane = tid & 63;
    const int w = tid >> 6;           // wave -> v-tile within each half-pair
    const int co = lane & 15;         // frag col (v)
    const int kq = lane >> 4;         // k-quad
    const int vlA = 16 * w + co;      // pair-local v, tile A (0..63)
    const int vlB = 64 + vlA;         // tile B (64..127)
    const int vgA = sorted[start + min(vlA, len - 1)];
    const int vgB = sorted[start + min(vlB, len - 1)];
    const float4* wpA = (const float4*)(W + (size_t)vgA * HH + kh * KQ + kq * 8);
    const float4* wpB = (const float4*)(W + (size_t)vgB * HH + kh * KQ + kq * 8);

    // one-shot burst: 24 outstanding 16B loads/lane (full K=192 for both tiles)
    float4 wfA[12], wfB[12];
#pragma unroll
    for (int kk = 0; kk < 6; ++kk) {
        wfA[2 * kk]     = wpA[kk * 8];
        wfA[2 * kk + 1] = wpA[kk * 8 + 1];
        wfB[2 * kk]     = wpB[kk * 8];
        wfB[2 * kk + 1] = wpB[kk * 8 + 1];
    }

    __syncthreads();

    const short* a0p = &OTlds[co * ST + kq * 8];
    f32x4 accA0 = {0.f,0.f,0.f,0.f}, accA1 = {0.f,0.f,0.f,0.f};
    f32x4 accB0 = {0.f,0.f,0.f,0.f}, accB1 = {0.f,0.f,0.f,0.f};
#pragma unroll
    for (int kk = 0; kk < 6; ++kk) {
        const short8v a0v = *(const short8v*)(a0p + kk * 32);
        const short8v a1v = *(const short8v*)(a0p + 16 * ST + kk * 32);
        short8v bfA, bfB;
        {
            const float4 f0 = wfA[2 * kk], f1 = wfA[2 * kk + 1];
            bfA[0]=f2bf(f0.x); bfA[1]=f2bf(f0.y); bfA[2]=f2bf(f0.z); bfA[3]=f2bf(f0.w);
            bfA[4]=f2bf(f1.x); bfA[5]=f2bf(f1.y); bfA[6]=f2bf(f1.z); bfA[7]=f2bf(f1.w);
        }
        {
            const float4 f0 = wfB[2 * kk], f1 = wfB[2 * kk + 1];
            bfB[0]=f2bf(f0.x); bfB[1]=f2bf(f0.y); bfB[2]=f2bf(f0.z); bfB[3]=f2bf(f0.w);
            bfB[4]=f2bf(f1.x); bfB[5]=f2bf(f1.y); bfB[6]=f2bf(f1.z); bfB[7]=f2bf(f1.w);
        }
        accA0 = __builtin_amdgcn_mfma_f32_16x16x32_bf16(a0v, bfA, accA0, 0, 0, 0);
        accA1 = __builtin_amdgcn_mfma_f32_16x16x32_bf16(a1v, bfA, accA1, 0, 0, 0);
        accB0 = __builtin_amdgcn_mfma_f32_16x16x32_bf16(a0v, bfB, accB0, 0, 0, 0);
        accB1 = __builtin_amdgcn_mfma_f32_16x16x32_bf16(a1v, bfB, accB1, 0, 0, 0);
    }

    // C[row=b][col=v]: row = kq*4 + reg (+16 for acc1), col = co (m89-verified)
    float* rpl = res + (size_t)(kh * BB) * SB + start;
    if (vlA < len) {
#pragma unroll
        for (int r2 = 0; r2 < 4; ++r2) {
            rpl[(size_t)(kq * 4 + r2) * SB + vlA]      = accA0[r2];
            rpl[(size_t)(16 + kq * 4 + r2) * SB + vlA] = accA1[r2];
        }
    }
    if (vlB < len) {
#pragma unroll
        for (int r2 = 0; r2 < 4; ++r2) {
            rpl[(size_t)(kq * 4 + r2) * SB + vlB]      = accB0[r2];
            rpl[(size_t)(16 + kq * 4 + r2) * SB + vlB] = accB1[r2];
        }
    }
}

// ---------- combine: gather 4 K-planes via posOf, coalesced out writes ------
__global__ void combine_k(const float* __restrict__ res, const int* __restrict__ posOf,
                          const float* __restrict__ bias, float* __restrict__ out) {
    const int v = blockIdx.x * 256 + threadIdx.x;
    if (v >= VV) return;
    const int b = blockIdx.y;
    const int pos = posOf[v];
    const float s = res[(size_t)b * SB + pos]
                  + res[(size_t)(BB + b) * SB + pos]
                  + res[(size_t)(2 * BB + b) * SB + pos]
                  + res[(size_t)(3 * BB + b) * SB + pos];
    out[(size_t)b * VV + v] = s + bias[v];
}

extern "C" void kernel_launch(void* const* d_in, const int* in_sizes, int n_in,
                              void* d_out, int out_size, void* d_ws, size_t ws_size,
                              hipStream_t stream) {
    const float* OT   = (const float*)d_in[0];  // [B,Q,H]
    const float* W    = (const float*)d_in[1];  // [V,H]
    const float* bias = (const float*)d_in[2];  // [V]
    const int*   pid  = (const int*)d_in[3];    // [V]
    float* out = (float*)d_out;                 // [B,V]

    char* ws = (char*)d_ws;
    int*   h      = (int*)(ws + WS_H);
    int*   base   = (int*)(ws + WS_BASE);
    int*   ntot   = (int*)(ws + WS_NTOT);
    int4*  desc   = (int4*)(ws + WS_DESC);
    int*   sorted = (int*)(ws + WS_SORTED);
    int*   posOf  = (int*)(ws + WS_POSOF);
    float* res    = (float*)(ws + WS_RES);

    hist_k<<<NB, 256, 0, stream>>>(pid, h);
    scan_k<<<1, 256, 0, stream>>>(h, base, desc, ntot);
    scatter_k<<<NB, 256, 0, stream>>>(pid, base, sorted, posOf);

    main_k<<<4 * MAXP, 256, 0, stream>>>(OT, W, sorted, desc, ntot, res);

    combine_k<<<dim3((VV + 255) / 256, BB), 256, 0, stream>>>(res, posOf, bias, out);
}

// Round 16
// 41.672 us; speedup vs baseline: 1.1982x; 1.1982x over previous
//
#include <hip/hip_runtime.h>
#include <hip/hip_bf16.h>

// out[b,v] = dot(OT[b, pid[v], :], W[v, :]) + bias[v]
// B=32, Q=180, H=768, V=19004. fp32 in/out, bf16 MFMA inside.
#define BB 32
#define QQ 180
#define HH 768
#define VV 19004
#define VB 64
#define KH 384       // K per half
#define SB 19008     // res stride (pos dim)
#define MAXDESC 480
#define STRIDE 392   // OT LDS row stride in bf16 elems (384 + 8 pad)
#define NB 80        // prep blocks
#define CH 238       // v's per prep block (80*238 = 19040 >= VV)

// ws layout (bytes)
#define WS_H      0        // NB*QQ ints = 57600
#define WS_NTOT   65536    // 1 int
#define WS_DESC   66560    // MAXDESC int4 = 7680
#define WS_SORTED 74752    // VV ints = 76016
#define WS_POSOF  151552   // VV ints = 76016
#define WS_RES    229376   // 2 * 32 * 19008 * 4 = 4,866,048

typedef __attribute__((ext_vector_type(8))) short short8v;  // 8 bf16 (4 VGPR)
typedef __attribute__((ext_vector_type(4))) float f32x4;

__device__ __forceinline__ unsigned pk2(float lo, float hi) {  // 2xbf16 RNE, packed
    __hip_bfloat162 r = __float22bfloat162_rn(make_float2(lo, hi));
    unsigned u;
    __builtin_memcpy(&u, &r, 4);
    return u;
}

// ---------- prep 1: per-block LDS histograms ----------
__global__ void hist_k(const int* __restrict__ pid, int* __restrict__ h) {
    __shared__ int lc[QQ];
    const int t = threadIdx.x, b = blockIdx.x;
    if (t < QQ) lc[t] = 0;
    __syncthreads();
    const int v = b * CH + t;
    if (t < CH && v < VV) atomicAdd(&lc[pid[v]], 1);
    __syncthreads();
    if (t < QQ) h[b * QQ + t] = lc[t];
}

// ---------- prep 2 (fused): local scan + scatter; block 0 emits desc/ntot ----
__global__ void scat_k(const int* __restrict__ pid, const int* __restrict__ h,
                       int* __restrict__ sorted, int* __restrict__ posOf,
                       int4* __restrict__ desc, int* __restrict__ ntot) {
    __shared__ int s1[256];
    __shared__ int s2[256];
    __shared__ int cur[QQ];
    const int t = threadIdx.x, b = blockIdx.x;
    int c = 0, mybase = 0;
    if (t < QQ) {
        for (int i = 0; i < NB; ++i) {       // column sum + prefix before b
            if (i == b) mybase = c;
            c += h[i * QQ + t];
        }
    }
    s1[t] = c;
    __syncthreads();
    for (int off = 1; off < 256; off <<= 1) {
        int a = (t >= off) ? s1[t - off] : 0;
        __syncthreads();
        s1[t] += a;
        __syncthreads();
    }
    const int qs = s1[t] - c;                // exclusive prefix over q
    if (t < QQ) cur[t] = qs + mybase;
    if (b == 0) {                            // desc + ntot (uniform branch)
        const int nch = (c + VB - 1) / VB;
        s2[t] = nch;
        __syncthreads();
        for (int off = 1; off < 256; off <<= 1) {
            int a = (t >= off) ? s2[t - off] : 0;
            __syncthreads();
            s2[t] += a;
            __syncthreads();
        }
        if (t < QQ) {
            const int cb = s2[t] - nch;
            for (int j = 0; j < nch; ++j)
                desc[cb + j] = make_int4(t, qs + j * VB, min(VB, c - j * VB), 0);
        }
        if (t == 255) *ntot = s2[255];
    }
    __syncthreads();
    const int v = b * CH + t;
    if (t < CH && v < VV) {
        const int q = pid[v];
        const int pos = atomicAdd(&cur[q], 1);   // LDS cursors, 1 block
        sorted[pos] = v;
        posOf[v] = pos;
    }
}

// ---------- main: MFMA 16x16x32 bf16, block = (chunk, K-half) — R12 shape ----
// 4 waves; wave w owns v-tile w (16 v's), both b-tiles, K=384 (12 steps x2
// MFMA). OT half staged once in LDS as bf16 (packed cvt); W burst-loaded (24
// outstanding float4/lane before the barrier). Full-line pos-space stores.
__launch_bounds__(256)
__global__ void main_k(const float* __restrict__ OT, const float* __restrict__ W,
                       const int* __restrict__ sorted, const int4* __restrict__ desc,
                       const int* __restrict__ ntot, float* __restrict__ res) {
    const int nt = *ntot;
    const int bid = blockIdx.x;
    const int ci = bid >> 1;
    if (ci >= nt) return;
    const int kh = bid & 1;
    const int4 d = desc[ci];
    const int q     = __builtin_amdgcn_readfirstlane(d.x);
    const int start = __builtin_amdgcn_readfirstlane(d.y);
    const int len   = __builtin_amdgcn_readfirstlane(d.z);
    const int tid = threadIdx.x;

    __shared__ short OTlds[BB * STRIDE];  // 25,088 B

    // stage OT[0..31][q][kh*384 .. +384) as bf16 (coalesced fp32 reads)
    {
        const int r = tid >> 3;   // b row 0..31
        const int o = tid & 7;    // octet
        const float* src = OT + ((size_t)r * QQ + q) * HH + kh * KH + o * 8;
        short* dst = &OTlds[r * STRIDE + o * 8];
#pragma unroll
        for (int it = 0; it < 6; ++it) {
            const float4 f0 = *(const float4*)(src + it * 64);
            const float4 f1 = *(const float4*)(src + it * 64 + 4);
            int4 p;
            p.x = (int)pk2(f0.x, f0.y); p.y = (int)pk2(f0.z, f0.w);
            p.z = (int)pk2(f1.x, f1.y); p.w = (int)pk2(f1.z, f1.w);
            *(int4*)(dst + it * 64) = p;
        }
    }

    const int lane = tid & 63;
    const int w = tid >> 6;           // v-tile
    const int co = lane & 15;         // frag col
    const int kq = lane >> 4;         // k-quad
    const int vl = 16 * w + co;       // v-local in chunk
    const int vg = sorted[start + min(vl, len - 1)];
    const float4* wp4 = (const float4*)(W + (size_t)vg * HH + kh * KH + kq * 8);
    const short* a0 = &OTlds[co * STRIDE + kq * 8];

    // burst: issue ALL W loads before any use (24 outstanding 16B/lane)
    float4 wf[24];
#pragma unroll
    for (int kk = 0; kk < 12; ++kk) {
        wf[2 * kk]     = wp4[kk * 8];
        wf[2 * kk + 1] = wp4[kk * 8 + 1];
    }

    __syncthreads();

    f32x4 acc0 = {0.f, 0.f, 0.f, 0.f};
    f32x4 acc1 = {0.f, 0.f, 0.f, 0.f};
#pragma unroll
    for (int kk = 0; kk < 12; ++kk) {
        const float4 wf0 = wf[2 * kk];
        const float4 wf1 = wf[2 * kk + 1];
        int4 p;
        p.x = (int)pk2(wf0.x, wf0.y); p.y = (int)pk2(wf0.z, wf0.w);
        p.z = (int)pk2(wf1.x, wf1.y); p.w = (int)pk2(wf1.z, wf1.w);
        short8v bf;
        __builtin_memcpy(&bf, &p, 16);
        const short8v a0v = *(const short8v*)(a0 + kk * 32);
        const short8v a1v = *(const short8v*)(a0 + 16 * STRIDE + kk * 32);
        acc0 = __builtin_amdgcn_mfma_f32_16x16x32_bf16(a0v, bf, acc0, 0, 0, 0);
        acc1 = __builtin_amdgcn_mfma_f32_16x16x32_bf16(a1v, bf, acc1, 0, 0, 0);
    }

    // C[row=b][col=v]: row = (lane>>4)*4 + reg, col = lane&15  (m89-verified)
    if (vl < len) {
        float* rp = res + (size_t)(kh * BB) * SB + start + vl;
#pragma unroll
        for (int r2 = 0; r2 < 4; ++r2) {
            rp[(size_t)(kq * 4 + r2) * SB]      = acc0[r2];
            rp[(size_t)(16 + kq * 4 + r2) * SB] = acc1[r2];
        }
    }
}

// ---------- combine: gather res via posOf (L2), coalesced out writes ----------
__global__ void combine_k(const float* __restrict__ res, const int* __restrict__ posOf,
                          const float* __restrict__ bias, float* __restrict__ out) {
    const int v = blockIdx.x * 256 + threadIdx.x;
    if (v >= VV) return;
    const int b = blockIdx.y;
    const int pos = posOf[v];
    const float s = res[(size_t)b * SB + pos] + res[(size_t)(BB + b) * SB + pos];
    out[(size_t)b * VV + v] = s + bias[v];
}

extern "C" void kernel_launch(void* const* d_in, const int* in_sizes, int n_in,
                              void* d_out, int out_size, void* d_ws, size_t ws_size,
                              hipStream_t stream) {
    const float* OT   = (const float*)d_in[0];  // [B,Q,H]
    const float* W    = (const float*)d_in[1];  // [V,H]
    const float* bias = (const float*)d_in[2];  // [V]
    const int*   pid  = (const int*)d_in[3];    // [V]
    float* out = (float*)d_out;                 // [B,V]

    char* ws = (char*)d_ws;
    int*   h      = (int*)(ws + WS_H);
    int*   ntot   = (int*)(ws + WS_NTOT);
    int4*  desc   = (int4*)(ws + WS_DESC);
    int*   sorted = (int*)(ws + WS_SORTED);
    int*   posOf  = (int*)(ws + WS_POSOF);
    float* res    = (float*)(ws + WS_RES);

    hist_k<<<NB, 256, 0, stream>>>(pid, h);
    scat_k<<<NB, 256, 0, stream>>>(pid, h, sorted, posOf, desc, ntot);

    main_k<<<2 * MAXDESC, 256, 0, stream>>>(OT, W, sorted, desc, ntot, res);

    combine_k<<<dim3((VV + 255) / 256, BB), 256, 0, stream>>>(res, posOf, bias, out);
}